// Round 11
// baseline (2654.692 us; speedup 1.0000x reference)
//
#include <hip/hip_runtime.h>

#define NPTS    2048
#define NBATCH  8
#define NPROB   24     // 8 batches x {xy, xx, yy}
#define NITER   30
#define TPB     512
#define WPB     8      // waves per block
#define NJOBS   32     // 16 row-chunks (128 rows) x 2 col-halves
#define HCOLS   1024   // columns per half
#define CPW     128    // columns per wave within a half

// eps = 0.05, log-domain Sinkhorn in log2 space.
constexpr float KSC = 28.853900817779268f;   // log2(e)/eps
constexpr float C1f = 0.38123094930796995f;  // eps*ln(2048)
constexpr float C2f = 0.03465735902799726f;  // eps*ln(2)
// Exact identities: KSC*C1f = log2(2048) = 11, KSC*C2f = 1
//  => staged potential K*phi = 11 - log2(sum_half0 + sum_half1)

__device__ __forceinline__ float fexp2(float x) { return __builtin_amdgcn_exp2f(x); }
__device__ __forceinline__ float flog2(float x) { return __builtin_amdgcn_logf(x); }
__device__ __forceinline__ float fsqrt(float x) { return __builtin_amdgcn_sqrtf(x); }

__global__ __launch_bounds__(256)
void init_sums(float* __restrict__ gsum)
{
    int i = blockIdx.x * 256 + threadIdx.x;
    if (i < NPROB * 2 * NPTS) gsum[i] = 1024.0f;   // halves sum to 2048 -> K*phi0 = 0
}

__device__ __forceinline__ void problem_barrier(unsigned* arrive, unsigned* epoch,
                                                unsigned phase, int nbpp, int tid)
{
    __syncthreads();   // drain all waves' work before the release RMW
    if (tid == 0) {
        unsigned old = __hip_atomic_fetch_add(arrive, 1u, __ATOMIC_ACQ_REL,
                                              __HIP_MEMORY_SCOPE_AGENT);
        if (old == (unsigned)(nbpp - 1)) {
            __hip_atomic_store(arrive, 0u, __ATOMIC_RELAXED, __HIP_MEMORY_SCOPE_AGENT);
            __hip_atomic_store(epoch, phase, __ATOMIC_RELEASE, __HIP_MEMORY_SCOPE_AGENT);
        } else {
            while (__hip_atomic_load(epoch, __ATOMIC_RELAXED,
                                     __HIP_MEMORY_SCOPE_AGENT) < phase) {
                __builtin_amdgcn_s_sleep(2);
            }
            __threadfence();   // acquire: fresh sums visible to this CU
        }
    }
    __syncthreads();
}

__global__ __launch_bounds__(TPB, 6)   // <=85 VGPR; 3 blocks/CU is all 768 blocks need
void sinkhorn_all(const float* __restrict__ xyz1,
                  const float* __restrict__ xyz2,
                  float* __restrict__ fsum,    // [NPROB][2][NPTS] raw partial sums
                  float* __restrict__ gsum,    // [NPROB][2][NPTS]
                  unsigned* __restrict__ bars,
                  int nbpp)
{
    __shared__ float4 shC[HCOLS];       // 16 KB: {x, y, z, K*phi} for one col-half
    __shared__ float  shS[WPB][128];    // 4 KB: per-wave partials (2 rows/lane)

    const int tid  = threadIdx.x;
    const int lane = tid & 63;
    const int warp = tid >> 6;
    const int p    = blockIdx.x % NPROB;   // blocks of one problem share an XCD (24%8==0)
    const int lb   = blockIdx.x / NPROB;
    const int b    = p / 3;
    const int k    = p - 3 * b;            // 0: xy, 1: xx, 2: yy

    const float* xb = xyz1 + (size_t)b * NPTS * 3;
    const float* yb = xyz2 + (size_t)b * NPTS * 3;
    float* fS = fsum + (size_t)p * 2 * NPTS;
    float* gS = gsum + (size_t)p * 2 * NPTS;
    unsigned* arrive = bars + (size_t)p * 64;
    unsigned* epoch  = bars + (size_t)p * 64 + 32;

    // rows/cols of the f-update and g-update
    const float* Uf = (k == 2) ? yb : xb;
    const float* Ug = (k == 0) ? yb : ((k == 1) ? xb : yb);
    const float* Vf = (k == 1) ? xb : yb;
    const float* Vg = (k == 2) ? yb : xb;

    // stage col-half h: coords (vectorized 3<->4 repack) + K*phi from raw sums
    auto stage = [&](const float* __restrict__ V, const float* __restrict__ S, int h) {
        if (tid < 256) {
            const float4* V4 = (const float4*)V;       // 16B-aligned (24KB batch stride)
            const int i0 = 3 * (h * 256 + tid);
            const float4 a  = V4[i0 + 0];
            const float4 bb = V4[i0 + 1];
            const float4 cc = V4[i0 + 2];
            const int c  = 4 * tid;                    // local col in half
            const int gc = h * HCOLS + c;              // global col
            const float4 t0 = *(const float4*)(S + gc);
            const float4 t1 = *(const float4*)(S + NPTS + gc);
            shC[c + 0] = make_float4(a.x,  a.y,  a.z,  11.0f - flog2(t0.x + t1.x));
            shC[c + 1] = make_float4(a.w,  bb.x, bb.y, 11.0f - flog2(t0.y + t1.y));
            shC[c + 2] = make_float4(bb.z, bb.w, cc.x, 11.0f - flog2(t0.z + t1.z));
            shC[c + 3] = make_float4(cc.y, cc.z, cc.w, 11.0f - flog2(t0.w + t1.w));
        }
    };

    // one job: 128 rows (2/lane) x this half's 1024 cols; writes raw partial sums
    auto do_pass = [&](const float* __restrict__ U, float* __restrict__ oS,
                       int h, int rc) {
        __syncthreads();                    // staging visible
        const int r0 = rc * 128 + lane, r1 = r0 + 64;
        const float ux0 = U[3*r0], uy0 = U[3*r0+1], uz0 = U[3*r0+2];
        const float ux1 = U[3*r1], uy1 = U[3*r1+1], uz1 = U[3*r1+2];
        float s00 = 0.f, s01 = 0.f, s02 = 0.f, s03 = 0.f;
        float s10 = 0.f, s11 = 0.f, s12 = 0.f, s13 = 0.f;
        auto term = [&](const float4 v, float ux, float uy, float uz) {
            float dx = ux - v.x, dy = uy - v.y, dz = uz - v.z;
            float d2 = fmaf(dx, dx, fmaf(dy, dy, fmaf(dz, dz, 1e-12f)));
            return fexp2(fmaf(-KSC, fsqrt(d2), v.w));
        };
        const int cb = warp * CPW;
        #pragma unroll 2
        for (int c = cb; c < cb + CPW; c += 4) {
            const float4 v0 = shC[c + 0];
            const float4 v1 = shC[c + 1];
            const float4 v2 = shC[c + 2];
            const float4 v3 = shC[c + 3];
            s00 += term(v0, ux0, uy0, uz0);  s10 += term(v0, ux1, uy1, uz1);
            s01 += term(v1, ux0, uy0, uz0);  s11 += term(v1, ux1, uy1, uz1);
            s02 += term(v2, ux0, uy0, uz0);  s12 += term(v2, ux1, uy1, uz1);
            s03 += term(v3, ux0, uy0, uz0);  s13 += term(v3, ux1, uy1, uz1);
        }
        shS[warp][lane]      = (s00 + s01) + (s02 + s03);
        shS[warp][lane + 64] = (s10 + s11) + (s12 + s13);
        __syncthreads();
        if (tid < 128) {                    // merge 8 col-slices; write raw SUM
            float t = shS[0][tid];
            #pragma unroll
            for (int w = 1; w < WPB; ++w) t += shS[w][tid];
            oS[h * NPTS + rc * 128 + tid] = t;   // coalesced 512B, disjoint per job
        }
        __syncthreads();                    // shC/shS safe for the next job's stage
    };

    for (int it = 0; it < NITER; ++it) {
        // f-pass: rows Uf vs cols Vf, potential = g (raw sums), out = fS
        for (int j = lb; j < NJOBS; j += nbpp) {
            stage(Vf, gS, j & 1);
            do_pass(Uf, fS, j & 1, j >> 1);
        }
        problem_barrier(arrive, epoch, (unsigned)(2 * it + 1), nbpp, tid);
        // g-pass: rows Ug vs cols Vg, potential = new f, out = gS
        for (int j = lb; j < NJOBS; j += nbpp) {
            stage(Vg, fS, j & 1);
            do_pass(Ug, gS, j & 1, j >> 1);
        }
        problem_barrier(arrive, epoch, (unsigned)(2 * it + 2), nbpp, tid);
    }
    // no grid.sync: kernel end is the fence; reduce runs as a separate launch
}

__global__ __launch_bounds__(TPB, 1)
void final_reduce(const float* __restrict__ fsum, const float* __restrict__ gsum,
                  float* __restrict__ out)
{
    __shared__ double red[WPB];
    const int tid  = threadIdx.x;
    const int lane = tid & 63;
    const int warp = tid >> 6;

    double acc = 0.0;
    for (int idx = tid; idx < 2 * NPROB * NPTS; idx += TPB) {
        const bool isF = idx < NPROB * NPTS;
        const int rem  = isF ? idx : idx - NPROB * NPTS;
        const int pp   = rem >> 11;            // / 2048
        const int j    = rem & (NPTS - 1);
        const float* S = (isF ? fsum : gsum) + (size_t)pp * 2 * NPTS;
        const float t  = S[j] + S[NPTS + j];
        const float val = C1f - C2f * flog2(t);
        const float w   = (pp % 3 == 0) ? 1.0f : -0.5f;
        acc += (double)val * (double)w;
    }
    #pragma unroll
    for (int off = 32; off > 0; off >>= 1) acc += __shfl_xor(acc, off);
    if (lane == 0) red[warp] = acc;
    __syncthreads();
    if (warp == 0) {
        double v2 = (lane < WPB) ? red[lane] : 0.0;
        #pragma unroll
        for (int off = 32; off > 0; off >>= 1) v2 += __shfl_xor(v2, off);
        if (lane == 0) out[0] = (float)(v2 / (double)(NBATCH * NPTS));
    }
}

extern "C" void kernel_launch(void* const* d_in, const int* in_sizes, int n_in,
                              void* d_out, int out_size, void* d_ws, size_t ws_size,
                              hipStream_t stream)
{
    const float* xyz1 = (const float*)d_in[0];
    const float* xyz2 = (const float*)d_in[1];
    float* out = (float*)d_out;

    float* fsum = (float*)d_ws;                       // 24*2*2048 floats
    float* gsum = fsum + (size_t)NPROB * 2 * NPTS;    // 24*2*2048 floats
    unsigned* bars = (unsigned*)(gsum + (size_t)NPROB * 2 * NPTS);

    // barrier state zero + g0 such that K*phi0 = 0 (deterministic per call)
    hipMemsetAsync(bars, 0, (size_t)NPROB * 64 * sizeof(unsigned), stream);
    init_sums<<<(NPROB * 2 * NPTS + 255) / 256, 256, 0, stream>>>(gsum);

    // co-residency-safe grid: clamp to what the runtime will actually co-schedule
    int maxB = 0;
    hipOccupancyMaxActiveBlocksPerMultiprocessor(&maxB, sinkhorn_all, TPB, 0);
    if (maxB < 1) maxB = 1;
    int bpp = (maxB * 256) / NPROB;
    if (bpp > NJOBS) bpp = NJOBS;
    if (bpp < 1) bpp = 1;
    int nblk = NPROB * bpp;

    void* args[] = { (void*)&xyz1, (void*)&xyz2, (void*)&fsum, (void*)&gsum,
                     (void*)&bars, (void*)&bpp };
    hipLaunchCooperativeKernel((void*)sinkhorn_all, dim3(nblk), dim3(TPB),
                               args, 0, stream);

    final_reduce<<<1, TPB, 0, stream>>>(fsum, gsum, out);
}

// Round 12
// 2348.734 us; speedup vs baseline: 1.1303x; 1.1303x over previous
//
#include <hip/hip_runtime.h>

#define NPTS    2048
#define NBATCH  8
#define NPROB   24     // 8 batches x {xy, xx, yy}
#define NITER   30
#define TPB     512
#define WPB     8      // waves per block
#define NJOBS   32     // 16 row-chunks (128 rows) x 2 col-halves
#define HCOLS   1024   // columns per half
#define CPW     128    // columns per wave within a half

// eps = 0.05, log-domain Sinkhorn in log2 space.
constexpr float KSC = 28.853900817779268f;   // log2(e)/eps
constexpr float C1f = 0.38123094930796995f;  // eps*ln(2048)
constexpr float C2f = 0.03465735902799726f;  // eps*ln(2)
// Exact identities: KSC*C1f = log2(2048) = 11, KSC*C2f = 1
//  => staged potential K*phi = 11 - log2(sum_half0 + sum_half1)

typedef float v2f __attribute__((ext_vector_type(2)));   // row0 = .x, row1 = .y (VGPR pair)

__device__ __forceinline__ float fexp2(float x) { return __builtin_amdgcn_exp2f(x); }
__device__ __forceinline__ float flog2(float x) { return __builtin_amdgcn_logf(x); }
__device__ __forceinline__ float fsqrt(float x) { return __builtin_amdgcn_sqrtf(x); }

__global__ __launch_bounds__(256)
void init_sums(float* __restrict__ gsum)
{
    int i = blockIdx.x * 256 + threadIdx.x;
    if (i < NPROB * 2 * NPTS) gsum[i] = 1024.0f;   // halves sum to 2048 -> K*phi0 = 0
}

__device__ __forceinline__ void problem_barrier(unsigned* arrive, unsigned* epoch,
                                                unsigned phase, int nbpp, int tid)
{
    __syncthreads();   // drain all waves' work before the release RMW
    if (tid == 0) {
        unsigned old = __hip_atomic_fetch_add(arrive, 1u, __ATOMIC_ACQ_REL,
                                              __HIP_MEMORY_SCOPE_AGENT);
        if (old == (unsigned)(nbpp - 1)) {
            __hip_atomic_store(arrive, 0u, __ATOMIC_RELAXED, __HIP_MEMORY_SCOPE_AGENT);
            __hip_atomic_store(epoch, phase, __ATOMIC_RELEASE, __HIP_MEMORY_SCOPE_AGENT);
        } else {
            while (__hip_atomic_load(epoch, __ATOMIC_RELAXED,
                                     __HIP_MEMORY_SCOPE_AGENT) < phase) {
                __builtin_amdgcn_s_sleep(2);
            }
            __threadfence();   // acquire: fresh sums visible to this CU
        }
    }
    __syncthreads();
}

__global__ __launch_bounds__(TPB, 6)
void sinkhorn_all(const float* __restrict__ xyz1,
                  const float* __restrict__ xyz2,
                  float* __restrict__ fsum,    // [NPROB][2][NPTS] raw partial sums
                  float* __restrict__ gsum,    // [NPROB][2][NPTS]
                  unsigned* __restrict__ bars,
                  int nbpp)
{
    __shared__ float4 shC[HCOLS];       // 16 KB: {x, y, z, K*phi} for one col-half
    __shared__ float  shS[WPB][128];    // 4 KB: per-wave partials (2 rows/lane)

    const int tid  = threadIdx.x;
    const int lane = tid & 63;
    const int warp = tid >> 6;
    const int p    = blockIdx.x % NPROB;   // blocks of one problem share an XCD (24%8==0)
    const int lb   = blockIdx.x / NPROB;
    const int b    = p / 3;
    const int k    = p - 3 * b;            // 0: xy, 1: xx, 2: yy

    const float* xb = xyz1 + (size_t)b * NPTS * 3;
    const float* yb = xyz2 + (size_t)b * NPTS * 3;
    float* fS = fsum + (size_t)p * 2 * NPTS;
    float* gS = gsum + (size_t)p * 2 * NPTS;
    unsigned* arrive = bars + (size_t)p * 64;
    unsigned* epoch  = bars + (size_t)p * 64 + 32;

    // rows/cols of the f-update and g-update
    const float* Uf = (k == 2) ? yb : xb;
    const float* Ug = (k == 0) ? yb : ((k == 1) ? xb : yb);
    const float* Vf = (k == 1) ? xb : yb;
    const float* Vg = (k == 2) ? yb : xb;

    // stage col-half h: coords (vectorized 3<->4 repack) + K*phi from raw sums
    auto stage = [&](const float* __restrict__ V, const float* __restrict__ S, int h) {
        if (tid < 256) {
            const float4* V4 = (const float4*)V;       // 16B-aligned (24KB batch stride)
            const int i0 = 3 * (h * 256 + tid);
            const float4 a  = V4[i0 + 0];
            const float4 bb = V4[i0 + 1];
            const float4 cc = V4[i0 + 2];
            const int c  = 4 * tid;                    // local col in half
            const int gc = h * HCOLS + c;              // global col
            const float4 t0 = *(const float4*)(S + gc);
            const float4 t1 = *(const float4*)(S + NPTS + gc);
            shC[c + 0] = make_float4(a.x,  a.y,  a.z,  11.0f - flog2(t0.x + t1.x));
            shC[c + 1] = make_float4(a.w,  bb.x, bb.y, 11.0f - flog2(t0.y + t1.y));
            shC[c + 2] = make_float4(bb.z, bb.w, cc.x, 11.0f - flog2(t0.z + t1.z));
            shC[c + 3] = make_float4(cc.y, cc.z, cc.w, 11.0f - flog2(t0.w + t1.w));
        }
    };

    // one job: 128 rows (2/lane, packed over VGPR pairs) x this half's 1024 cols
    auto do_pass = [&](const float* __restrict__ U, float* __restrict__ oS,
                       int h, int rc) {
        __syncthreads();                    // staging visible
        const int r0 = rc * 128 + lane, r1 = r0 + 64;
        const v2f ux = {U[3*r0],   U[3*r1]};
        const v2f uy = {U[3*r0+1], U[3*r1+1]};
        const v2f uz = {U[3*r0+2], U[3*r1+2]};
        const v2f e12 = {1e-12f, 1e-12f};
        const v2f nK  = {-KSC, -KSC};
        v2f s0 = {0.f, 0.f}, s1 = {0.f, 0.f}, s2 = {0.f, 0.f}, s3 = {0.f, 0.f};

        // ROUND-12 CHANGE: both rows per op via packed fp32 (v_pk_*_f32).
        // Per-component arithmetic/order bitwise identical to round 11.
        auto term = [&](const float4 v) -> v2f {
            v2f dx = ux - (v2f){v.x, v.x};
            v2f dy = uy - (v2f){v.y, v.y};
            v2f dz = uz - (v2f){v.z, v.z};
            v2f d2 = __builtin_elementwise_fma(dz, dz, e12);
            d2 = __builtin_elementwise_fma(dy, dy, d2);
            d2 = __builtin_elementwise_fma(dx, dx, d2);
            v2f sq  = {fsqrt(d2.x), fsqrt(d2.y)};        // .x/.y are the pair's regs: free
            v2f arg = __builtin_elementwise_fma(nK, sq, (v2f){v.w, v.w});
            return (v2f){fexp2(arg.x), fexp2(arg.y)};
        };
        const int cb = warp * CPW;
        #pragma unroll 2
        for (int c = cb; c < cb + CPW; c += 4) {
            const float4 v0 = shC[c + 0];
            const float4 v1 = shC[c + 1];
            const float4 v2 = shC[c + 2];
            const float4 v3 = shC[c + 3];
            s0 += term(v0);
            s1 += term(v1);
            s2 += term(v2);
            s3 += term(v3);
        }
        shS[warp][lane]      = (s0.x + s1.x) + (s2.x + s3.x);
        shS[warp][lane + 64] = (s0.y + s1.y) + (s2.y + s3.y);
        __syncthreads();
        if (tid < 128) {                    // merge 8 col-slices; write raw SUM
            float t = shS[0][tid];
            #pragma unroll
            for (int w = 1; w < WPB; ++w) t += shS[w][tid];
            oS[h * NPTS + rc * 128 + tid] = t;   // coalesced 512B, disjoint per job
        }
        __syncthreads();                    // shC/shS safe for the next job's stage
    };

    for (int it = 0; it < NITER; ++it) {
        // f-pass: rows Uf vs cols Vf, potential = g (raw sums), out = fS
        for (int j = lb; j < NJOBS; j += nbpp) {
            stage(Vf, gS, j & 1);
            do_pass(Uf, fS, j & 1, j >> 1);
        }
        problem_barrier(arrive, epoch, (unsigned)(2 * it + 1), nbpp, tid);
        // g-pass: rows Ug vs cols Vg, potential = new f, out = gS
        for (int j = lb; j < NJOBS; j += nbpp) {
            stage(Vg, fS, j & 1);
            do_pass(Ug, gS, j & 1, j >> 1);
        }
        problem_barrier(arrive, epoch, (unsigned)(2 * it + 2), nbpp, tid);
    }
    // no grid.sync: kernel end is the fence; reduce runs as a separate launch
}

__global__ __launch_bounds__(TPB, 1)
void final_reduce(const float* __restrict__ fsum, const float* __restrict__ gsum,
                  float* __restrict__ out)
{
    __shared__ double red[WPB];
    const int tid  = threadIdx.x;
    const int lane = tid & 63;
    const int warp = tid >> 6;

    double acc = 0.0;
    for (int idx = tid; idx < 2 * NPROB * NPTS; idx += TPB) {
        const bool isF = idx < NPROB * NPTS;
        const int rem  = isF ? idx : idx - NPROB * NPTS;
        const int pp   = rem >> 11;            // / 2048
        const int j    = rem & (NPTS - 1);
        const float* S = (isF ? fsum : gsum) + (size_t)pp * 2 * NPTS;
        const float t  = S[j] + S[NPTS + j];
        const float val = C1f - C2f * flog2(t);
        const float w   = (pp % 3 == 0) ? 1.0f : -0.5f;
        acc += (double)val * (double)w;
    }
    #pragma unroll
    for (int off = 32; off > 0; off >>= 1) acc += __shfl_xor(acc, off);
    if (lane == 0) red[warp] = acc;
    __syncthreads();
    if (warp == 0) {
        double v2 = (lane < WPB) ? red[lane] : 0.0;
        #pragma unroll
        for (int off = 32; off > 0; off >>= 1) v2 += __shfl_xor(v2, off);
        if (lane == 0) out[0] = (float)(v2 / (double)(NBATCH * NPTS));
    }
}

extern "C" void kernel_launch(void* const* d_in, const int* in_sizes, int n_in,
                              void* d_out, int out_size, void* d_ws, size_t ws_size,
                              hipStream_t stream)
{
    const float* xyz1 = (const float*)d_in[0];
    const float* xyz2 = (const float*)d_in[1];
    float* out = (float*)d_out;

    float* fsum = (float*)d_ws;                       // 24*2*2048 floats
    float* gsum = fsum + (size_t)NPROB * 2 * NPTS;    // 24*2*2048 floats
    unsigned* bars = (unsigned*)(gsum + (size_t)NPROB * 2 * NPTS);

    // barrier state zero + g0 such that K*phi0 = 0 (deterministic per call)
    hipMemsetAsync(bars, 0, (size_t)NPROB * 64 * sizeof(unsigned), stream);
    init_sums<<<(NPROB * 2 * NPTS + 255) / 256, 256, 0, stream>>>(gsum);

    // co-residency-safe grid: clamp to what the runtime will actually co-schedule
    int maxB = 0;
    hipOccupancyMaxActiveBlocksPerMultiprocessor(&maxB, sinkhorn_all, TPB, 0);
    if (maxB < 1) maxB = 1;
    int bpp = (maxB * 256) / NPROB;
    if (bpp > NJOBS) bpp = NJOBS;
    if (bpp < 1) bpp = 1;
    int nblk = NPROB * bpp;

    void* args[] = { (void*)&xyz1, (void*)&xyz2, (void*)&fsum, (void*)&gsum,
                     (void*)&bars, (void*)&bpp };
    hipLaunchCooperativeKernel((void*)sinkhorn_all, dim3(nblk), dim3(TPB),
                               args, 0, stream);

    final_reduce<<<1, TPB, 0, stream>>>(fsum, gsum, out);
}